// Round 2
// baseline (294.403 us; speedup 1.0000x reference)
//
#include <hip/hip_runtime.h>
#include <hip/hip_bf16.h>

#define E_TOT 200000
#define NZ 64
#define ATTR_D 768
#define KD 832          // 64 + 768
#define HID_D 128
#define NCLS 5
#define NKT 26          // K steps of 32

typedef __attribute__((ext_vector_type(8))) short short8;   // 8 bf16 (4 VGPRs)
typedef __attribute__((ext_vector_type(4))) float f32x4;    // MFMA accumulator

__device__ __forceinline__ unsigned pk2(float a, float b) {
    __hip_bfloat162 h = __float22bfloat162_rn(make_float2(a, b));
    return *reinterpret_cast<unsigned*>(&h);
}

__device__ __forceinline__ short8 pack8(const float4 x0, const float4 x1) {
    union { unsigned u[4]; short8 s; } r;
    r.u[0] = pk2(x0.x, x0.y);
    r.u[1] = pk2(x0.z, x0.w);
    r.u[2] = pk2(x1.x, x1.y);
    r.u[3] = pk2(x1.z, x1.w);
    return r.s;
}

// ---- prep: W1 [832][128] f32 -> W1t [128][832] bf16 (transposed, contiguous B frags)
__global__ void prep_w1t(const float* __restrict__ W1, __hip_bfloat16* __restrict__ w1t) {
    int idx = blockIdx.x * 256 + threadIdx.x;
    if (idx >= HID_D * KD) return;
    int n = idx / KD;
    int k = idx - n * KD;
    w1t[idx] = __float2bfloat16(W1[(size_t)k * HID_D + n]);
}

// ---- main: LDS-free streaming GEMM. Block = 4 waves x 32 edge rows = 128 edges.
// Per wave: 2 M-frags x 8 N-frags of 16x16x32 bf16 MFMA, K=832 in 26 steps,
// A and B register-double-buffered with 1-step prefetch. Fused MLP2+softmax epilogue.
__global__ __launch_bounds__(256, 2) void gcn_main(
    const float* __restrict__ z, const int* __restrict__ ei,
    const float* __restrict__ attr, const __hip_bfloat16* __restrict__ w1t,
    const float* __restrict__ b1, const float* __restrict__ W2,
    const float* __restrict__ b2, float* __restrict__ out) {

    const int t    = threadIdx.x;
    const int wv   = t >> 6;        // wave 0..3 -> rows [wv*32, wv*32+32)
    const int lane = t & 63;
    const int g    = lane >> 4;     // k-group: elements g*8..g*8+7 of the 32-slice
    const int c0   = lane & 15;     // A row within frag / B col within frag
    const int e0   = blockIdx.x * 128;

    // per-M-frag row pointers (clamped for OOB rows; their results are never written)
    const float* ab[2];
    const float* zs[2];
    const float* zd[2];
#pragma unroll
    for (int m = 0; m < 2; ++m) {
        int e  = e0 + wv * 32 + m * 16 + c0;
        int ec = e < E_TOT ? e : E_TOT - 1;
        ab[m] = attr + (size_t)ec * ATTR_D + g * 8;
        int si = ei[ec];
        int di = ei[E_TOT + ec];
        zs[m] = z + (size_t)si * NZ + g * 8;
        zd[m] = z + (size_t)di * NZ + g * 8;
    }
    const __hip_bfloat16* wbase = w1t + (size_t)c0 * KD + g * 8;

    auto LOADB = [&](int kt, short8 (&b)[8]) {
#pragma unroll
        for (int f = 0; f < 8; ++f)
            b[f] = *reinterpret_cast<const short8*>(wbase + f * 16 * KD + kt * 32);
    };
    auto LOADA = [&](int kt, float4 (&ar)[2][2]) {
        if (kt >= 2) {              // edge_attr part, k in [64, 832)
            const int off = kt * 32 - NZ;
#pragma unroll
            for (int m = 0; m < 2; ++m) {
                const float4* p = reinterpret_cast<const float4*>(ab[m] + off);
                ar[m][0] = p[0];
                ar[m][1] = p[1];
            }
        } else {                    // node_rep = z[src]*z[dst], k in [0, 64)
            const int off = kt * 32;
#pragma unroll
            for (int m = 0; m < 2; ++m) {
                const float4* ps = reinterpret_cast<const float4*>(zs[m] + off);
                const float4* pd = reinterpret_cast<const float4*>(zd[m] + off);
                float4 s0 = ps[0], s1 = ps[1];
                float4 d0 = pd[0], d1 = pd[1];
                ar[m][0] = make_float4(s0.x * d0.x, s0.y * d0.y, s0.z * d0.z, s0.w * d0.w);
                ar[m][1] = make_float4(s1.x * d1.x, s1.y * d1.y, s1.z * d1.z, s1.w * d1.w);
            }
        }
    };

    f32x4 acc[2][8];
#pragma unroll
    for (int m = 0; m < 2; ++m)
#pragma unroll
        for (int f = 0; f < 8; ++f) acc[m][f] = (f32x4){0.f, 0.f, 0.f, 0.f};

    float4 arA[2][2], arB[2][2];
    short8 bA[8], bB[8];
    LOADB(0, bA);
    LOADA(0, arA);

    for (int kt = 0; kt < NKT; kt += 2) {
        // even step: compute kt from (arA,bA); prefetch kt+1 -> (arB,bB)
        LOADB(kt + 1, bB);
        LOADA(kt + 1, arB);
        {
            short8 a0 = pack8(arA[0][0], arA[0][1]);
            short8 a1 = pack8(arA[1][0], arA[1][1]);
#pragma unroll
            for (int f = 0; f < 8; ++f) {
                acc[0][f] = __builtin_amdgcn_mfma_f32_16x16x32_bf16(a0, bA[f], acc[0][f], 0, 0, 0);
                acc[1][f] = __builtin_amdgcn_mfma_f32_16x16x32_bf16(a1, bA[f], acc[1][f], 0, 0, 0);
            }
        }
        // odd step: compute kt+1 from (arB,bB); prefetch kt+2 -> (arA,bA)
        if (kt + 2 < NKT) {
            LOADB(kt + 2, bA);
            LOADA(kt + 2, arA);
        }
        {
            short8 a0 = pack8(arB[0][0], arB[0][1]);
            short8 a1 = pack8(arB[1][0], arB[1][1]);
#pragma unroll
            for (int f = 0; f < 8; ++f) {
                acc[0][f] = __builtin_amdgcn_mfma_f32_16x16x32_bf16(a0, bB[f], acc[0][f], 0, 0, 0);
                acc[1][f] = __builtin_amdgcn_mfma_f32_16x16x32_bf16(a1, bB[f], acc[1][f], 0, 0, 0);
            }
        }
    }

    // ---- epilogue: h = relu(acc + b1); logits = h @ W2 + b2; softmax; write
    float b1v[8], w2v[8][NCLS];
#pragma unroll
    for (int f = 0; f < 8; ++f) {
        int col = f * 16 + c0;
        b1v[f] = b1[col];
#pragma unroll
        for (int cc = 0; cc < NCLS; ++cc) w2v[f][cc] = W2[col * NCLS + cc];
    }
    float b2v[NCLS];
#pragma unroll
    for (int cc = 0; cc < NCLS; ++cc) b2v[cc] = b2[cc];

#pragma unroll
    for (int m = 0; m < 2; ++m) {
#pragma unroll
        for (int i = 0; i < 4; ++i) {
            float lg[NCLS] = {0.f, 0.f, 0.f, 0.f, 0.f};
#pragma unroll
            for (int f = 0; f < 8; ++f) {
                float h = acc[m][f][i] + b1v[f];
                h = fmaxf(h, 0.f);
#pragma unroll
                for (int cc = 0; cc < NCLS; ++cc) lg[cc] = fmaf(h, w2v[f][cc], lg[cc]);
            }
            // reduce across the 16 lanes (same g) holding this row's 128 columns
#pragma unroll
            for (int mask = 1; mask < 16; mask <<= 1) {
#pragma unroll
                for (int cc = 0; cc < NCLS; ++cc) lg[cc] += __shfl_xor(lg[cc], mask);
            }
#pragma unroll
            for (int cc = 0; cc < NCLS; ++cc) lg[cc] += b2v[cc];

            float mx = fmaxf(fmaxf(fmaxf(lg[0], lg[1]), fmaxf(lg[2], lg[3])), lg[4]);
            float q[NCLS];
            float s = 0.f;
#pragma unroll
            for (int cc = 0; cc < NCLS; ++cc) { q[cc] = __expf(lg[cc] - mx); s += q[cc]; }
            float inv = 1.0f / s;
            float num = (c0 == 0) ? q[0] : (c0 == 1) ? q[1] : (c0 == 2) ? q[2]
                      : (c0 == 3) ? q[3] : q[4];
            int rowl = wv * 32 + m * 16 + g * 4 + i;
            int eo = e0 + rowl;
            if (eo < E_TOT && c0 < NCLS) out[(size_t)eo * NCLS + c0] = num * inv;
        }
    }
}

extern "C" void kernel_launch(void* const* d_in, const int* in_sizes, int n_in,
                              void* d_out, int out_size, void* d_ws, size_t ws_size,
                              hipStream_t stream) {
    const float* z    = (const float*)d_in[0];
    const int*   ei   = (const int*)d_in[1];
    const float* attr = (const float*)d_in[2];
    const float* W1   = (const float*)d_in[3];
    const float* b1   = (const float*)d_in[4];
    const float* W2   = (const float*)d_in[5];
    const float* b2   = (const float*)d_in[6];
    float* out = (float*)d_out;
    __hip_bfloat16* w1t = (__hip_bfloat16*)d_ws;   // 128*832*2 = 212992 B

    prep_w1t<<<(HID_D * KD + 255) / 256, 256, 0, stream>>>(W1, w1t);
    const int nblk = (E_TOT + 127) / 128;   // 1563
    gcn_main<<<nblk, 256, 0, stream>>>(z, ei, attr, w1t, b1, W2, b2, out);
}

// Round 3
// 174.476 us; speedup vs baseline: 1.6874x; 1.6874x over previous
//
#include <hip/hip_runtime.h>
#include <hip/hip_bf16.h>

#define E_TOT 200000
#define NZ 64
#define ATTR_D 768
#define KD 832          // 64 + 768
#define HID_D 128
#define NCLS 5
#define NAT 24          // attr K-steps of 32 floats (kt = 2..25)

typedef __attribute__((ext_vector_type(8))) short short8;   // 8 bf16 (4 VGPRs)
typedef __attribute__((ext_vector_type(4))) float f32x4;    // MFMA accumulator

typedef __attribute__((address_space(3))) unsigned       lds_u32_t;
typedef const __attribute__((address_space(1))) unsigned glob_u32_t;

__device__ __forceinline__ unsigned pk2(float a, float b) {
    __hip_bfloat162 h = __float22bfloat162_rn(make_float2(a, b));
    return *reinterpret_cast<unsigned*>(&h);
}

__device__ __forceinline__ short8 pack8(const float4 x0, const float4 x1) {
    union { unsigned u[4]; short8 s; } r;
    r.u[0] = pk2(x0.x, x0.y);
    r.u[1] = pk2(x0.z, x0.w);
    r.u[2] = pk2(x1.x, x1.y);
    r.u[3] = pk2(x1.z, x1.w);
    return r.s;
}

// ---- prep: W1 [832][128] f32 -> frag-ordered bf16 w1f[kt][f][lane][8]
// value = W1t[n = f*16 + (lane&15)][k = kt*32 + (lane>>4)*8 + j]
__global__ void prep_w1f(const float* __restrict__ W1, __hip_bfloat16* __restrict__ w1f) {
    int idx = blockIdx.x * 256 + threadIdx.x;       // over 26*8*64*8 = 106496
    if (idx >= 26 * 8 * 64 * 8) return;
    int j    = idx & 7;
    int lane = (idx >> 3) & 63;
    int f    = (idx >> 9) & 7;
    int kt   = idx >> 12;
    int n = f * 16 + (lane & 15);
    int k = kt * 32 + (lane >> 4) * 8 + j;
    w1f[idx] = __float2bfloat16(W1[(size_t)k * HID_D + n]);
}

// ---- main: 128 edges x 128 hid per block, 4 waves, fused MLP+softmax.
// attr staged f32 via global_load_lds (16B), double-buffered, 1-step prefetch.
// Source-side XOR swizzle (chunk ^= row&7) keeps ds_read_b128 spread over all banks.
__global__ __launch_bounds__(256, 2) void gcn_main(
    const float* __restrict__ z, const int* __restrict__ ei,
    const float* __restrict__ attr, const __hip_bfloat16* __restrict__ w1f,
    const float* __restrict__ b1, const float* __restrict__ W2,
    const float* __restrict__ b2, float* __restrict__ out) {

    __shared__ float As[2][128 * 32];   // 2 x 16 KB, row = 32 f32 = 8 chunks of 16B

    const int t    = threadIdx.x;
    const int wv   = t >> 6;
    const int lane = t & 63;
    const int g    = lane >> 4;     // k-group
    const int c0   = lane & 15;
    const int e0   = blockIdx.x * 128;

    // ---- staging source pointers: 4 x 16B per thread per step; LDS stays linear,
    // the chunk permutation c = p ^ (row&7) is applied to the GLOBAL source.
    const float* sbase[4];
#pragma unroll
    for (int i = 0; i < 4; ++i) {
        int L   = wv * 1024 + i * 4096 + lane * 16;   // linear LDS byte this lane covers
        int row = L >> 7;                             // 128B per row
        int p   = (L >> 4) & 7;                       // physical 16B chunk slot
        int c   = p ^ (row & 7);                      // logical chunk stored there
        int er  = e0 + row; if (er >= E_TOT) er = E_TOT - 1;
        sbase[i] = attr + (size_t)er * ATTR_D + c * 4;
    }

    auto STAGE = [&](int buf, int at) {
#pragma unroll
        for (int i = 0; i < 4; ++i) {
            __builtin_amdgcn_global_load_lds(
                (glob_u32_t*)(sbase[i] + at * 32),
                (lds_u32_t*)&As[buf][wv * 256 + i * 1024],
                16, 0, 0);
        }
    };

    const __hip_bfloat16* wf = w1f + (size_t)lane * 8;
    auto LOADB = [&](int kt, short8(&b)[8]) {
#pragma unroll
        for (int f = 0; f < 8; ++f)
            b[f] = *reinterpret_cast<const short8*>(wf + (size_t)(kt * 8 + f) * 512);
    };

    // ---- z-gather pointers (clamped; clamped rows' results never written)
    const float* zsp[2];
    const float* zdp[2];
#pragma unroll
    for (int m = 0; m < 2; ++m) {
        int e = e0 + wv * 32 + m * 16 + c0; if (e >= E_TOT) e = E_TOT - 1;
        int si = ei[e];
        int di = ei[E_TOT + e];
        zsp[m] = z + (size_t)si * NZ + g * 8;
        zdp[m] = z + (size_t)di * NZ + g * 8;
    }

    f32x4 acc[2][8];
#pragma unroll
    for (int m = 0; m < 2; ++m)
#pragma unroll
        for (int f = 0; f < 8; ++f) acc[m][f] = (f32x4){0.f, 0.f, 0.f, 0.f};

    // ---- prologue: start the attr stream ASAP, hide it behind the z-phase
    STAGE(0, 0);

    {
        short8 bz0[8], bz1[8];
        LOADB(0, bz0);
        LOADB(1, bz1);
#pragma unroll
        for (int kt = 0; kt < 2; ++kt) {
            short8 a[2];
#pragma unroll
            for (int m = 0; m < 2; ++m) {
                const float4* ps = reinterpret_cast<const float4*>(zsp[m] + kt * 32);
                const float4* pd = reinterpret_cast<const float4*>(zdp[m] + kt * 32);
                float4 s0 = ps[0], s1 = ps[1];
                float4 d0 = pd[0], d1 = pd[1];
                float4 x0 = make_float4(s0.x * d0.x, s0.y * d0.y, s0.z * d0.z, s0.w * d0.w);
                float4 x1 = make_float4(s1.x * d1.x, s1.y * d1.y, s1.z * d1.z, s1.w * d1.w);
                a[m] = pack8(x0, x1);
            }
#pragma unroll
            for (int f = 0; f < 8; ++f) {
                short8 bb = kt ? bz1[f] : bz0[f];
                acc[0][f] = __builtin_amdgcn_mfma_f32_16x16x32_bf16(a[0], bb, acc[0][f], 0, 0, 0);
                acc[1][f] = __builtin_amdgcn_mfma_f32_16x16x32_bf16(a[1], bb, acc[1][f], 0, 0, 0);
            }
        }
    }

    short8 bC[8], bN[8];
    LOADB(2, bC);
    __syncthreads();    // drains vmcnt -> buf0 staged

    // ---- main pipeline: compute at (kt=at+2) from As[cur], stage at+1 into As[cur^1]
    for (int at = 0; at < NAT; ++at) {
        const int cur = at & 1;
        if (at + 1 < NAT) STAGE(cur ^ 1, at + 1);
        const int ktn = (at + 3 <= 25) ? at + 3 : 25;
        LOADB(ktn, bN);

        short8 a[2];
#pragma unroll
        for (int m = 0; m < 2; ++m) {
            int r    = wv * 32 + m * 16 + c0;
            int base = r * 32;
            int p0   = ((g * 2)     ^ (r & 7)) * 4;
            int p1   = ((g * 2 + 1) ^ (r & 7)) * 4;
            float4 x0 = *reinterpret_cast<const float4*>(&As[cur][base + p0]);
            float4 x1 = *reinterpret_cast<const float4*>(&As[cur][base + p1]);
            a[m] = pack8(x0, x1);
        }
#pragma unroll
        for (int f = 0; f < 8; ++f) {
            acc[0][f] = __builtin_amdgcn_mfma_f32_16x16x32_bf16(a[0], bC[f], acc[0][f], 0, 0, 0);
            acc[1][f] = __builtin_amdgcn_mfma_f32_16x16x32_bf16(a[1], bC[f], acc[1][f], 0, 0, 0);
        }
        __syncthreads();    // single drain per step: next buffer staged, reads done
#pragma unroll
        for (int f = 0; f < 8; ++f) bC[f] = bN[f];
    }

    // ---- epilogue: h = relu(acc + b1); logits = h @ W2 + b2; softmax; write
    float b1v[8], w2v[8][NCLS];
#pragma unroll
    for (int f = 0; f < 8; ++f) {
        int col = f * 16 + c0;
        b1v[f] = b1[col];
#pragma unroll
        for (int cc = 0; cc < NCLS; ++cc) w2v[f][cc] = W2[col * NCLS + cc];
    }
    float b2v[NCLS];
#pragma unroll
    for (int cc = 0; cc < NCLS; ++cc) b2v[cc] = b2[cc];

#pragma unroll
    for (int m = 0; m < 2; ++m) {
#pragma unroll
        for (int i = 0; i < 4; ++i) {
            float lg[NCLS] = {0.f, 0.f, 0.f, 0.f, 0.f};
#pragma unroll
            for (int f = 0; f < 8; ++f) {
                float h = acc[m][f][i] + b1v[f];
                h = fmaxf(h, 0.f);
#pragma unroll
                for (int cc = 0; cc < NCLS; ++cc) lg[cc] = fmaf(h, w2v[f][cc], lg[cc]);
            }
#pragma unroll
            for (int mask = 1; mask < 16; mask <<= 1) {
#pragma unroll
                for (int cc = 0; cc < NCLS; ++cc) lg[cc] += __shfl_xor(lg[cc], mask);
            }
#pragma unroll
            for (int cc = 0; cc < NCLS; ++cc) lg[cc] += b2v[cc];

            float mx = fmaxf(fmaxf(fmaxf(lg[0], lg[1]), fmaxf(lg[2], lg[3])), lg[4]);
            float q[NCLS];
            float s = 0.f;
#pragma unroll
            for (int cc = 0; cc < NCLS; ++cc) { q[cc] = __expf(lg[cc] - mx); s += q[cc]; }
            float inv = 1.0f / s;
            float num = (c0 == 0) ? q[0] : (c0 == 1) ? q[1] : (c0 == 2) ? q[2]
                      : (c0 == 3) ? q[3] : q[4];
            int rowl = wv * 32 + m * 16 + g * 4 + i;
            int eo = e0 + rowl;
            if (eo < E_TOT && c0 < NCLS) out[(size_t)eo * NCLS + c0] = num * inv;
        }
    }
}

extern "C" void kernel_launch(void* const* d_in, const int* in_sizes, int n_in,
                              void* d_out, int out_size, void* d_ws, size_t ws_size,
                              hipStream_t stream) {
    const float* z    = (const float*)d_in[0];
    const int*   ei   = (const int*)d_in[1];
    const float* attr = (const float*)d_in[2];
    const float* W1   = (const float*)d_in[3];
    const float* b1   = (const float*)d_in[4];
    const float* W2   = (const float*)d_in[5];
    const float* b2   = (const float*)d_in[6];
    float* out = (float*)d_out;
    __hip_bfloat16* w1f = (__hip_bfloat16*)d_ws;   // 26*8*64*8*2 = 212992 B

    prep_w1f<<<(26 * 8 * 64 * 8 + 255) / 256, 256, 0, stream>>>(W1, w1f);
    const int nblk = (E_TOT + 127) / 128;   // 1563
    gcn_main<<<nblk, 256, 0, stream>>>(z, ei, attr, w1f, b1, W2, b2, out);
}